// Round 3
// baseline (173.255 us; speedup 1.0000x reference)
//
#include <hip/hip_runtime.h>
#include <math.h>

// Depth collapses to d=0 (x[:, :, 0:1] slicing): conv1d -> w[3]*xi+b,
// scan at d=0 -> hs[0]=BX[0] (A_log unused), y = xi*(delta*sum(B*C)+D).
#define NB   2
#define CM   96      // D_MODEL
#define CI   192     // D_INNER
#define CO   384     // 2*D_INNER
#define HP   24
#define WP   24
#define PX   576
#define DTR  6
#define NDBC 38
#define CSPLIT 4
#define CCH  24      // input channels per conv chunk
#define ROWS 2       // output rows per conv block

__device__ __forceinline__ float siluf(float x){ return x / (1.f + expf(-x)); }
__device__ __forceinline__ float softplusf(float x){ return x > 20.f ? x : log1pf(expf(x)); }
__device__ __forceinline__ unsigned short f2bf(float f){
    unsigned u = __float_as_uint(f);
    return (unsigned short)((u + 0x7fffu + ((u >> 16) & 1u)) >> 16);
}
__device__ __forceinline__ float bflo(unsigned u){ return __uint_as_float(u << 16); }
__device__ __forceinline__ float bfhi(unsigned u){ return __uint_as_float(u & 0xffff0000u); }

// ---- prep: pack in_proj weights to bf16: wQb[l][c][o][k0..7] (ushort8 = uint4)
//            + wRb[l][c][o] (tap 8), and transpose out_proj -> wpT[l][c][m] fp32
#define NW_IN (2*CO*CM*9)      // 663552
#define WQB_L (CM*CO*8)        // ushorts per layer
#define WRB_L (CM*CO)
#define WPT_L (CI*CM)
__global__ void prep_k(const float* __restrict__ ipw, const float* __restrict__ opw,
                       unsigned short* __restrict__ wQb, unsigned short* __restrict__ wRb,
                       float* __restrict__ wpT){
    int idx = blockIdx.x*256 + threadIdx.x;
    if (idx < NW_IN){
        int l = idx / (CO*CM*9);
        int r = idx % (CO*CM*9);
        int o = r / (CM*9);
        int r2 = r % (CM*9);
        int c = r2 / 9;
        int k = r2 % 9;
        unsigned short v = f2bf(ipw[idx]);
        if (k < 8) wQb[(long)l*WQB_L + ((c*CO + o)<<3) + k] = v;
        else       wRb[(long)l*WRB_L + c*CO + o] = v;
    } else {
        int j = idx - NW_IN;
        if (j < 2*CI*CM){
            int l = j / (CI*CM);
            int r = j % (CI*CM);
            int c = r / CM;
            int m = r % CM;
            wpT[l*WPT_L + c*CM + m] = opw[(l*CM + m)*CI + c];
        }
    }
}

// ---- conv: fused rmsnorm + 3x3 conv (pad 1), bf16 weights, fp32 accum.
// grid (NB*HP/ROWS, 6 o-groups, CSPLIT c-chunks), block 256.
// Each thread: one o, one 6-px strip, both rows -> 12 accumulators.
// acc layout: [cs][n][px][o]
__global__ __launch_bounds__(256) void conv_k(
    const float* __restrict__ x, long nStr, long cStr,
    const float* __restrict__ nw,
    const unsigned short* __restrict__ wQb, const unsigned short* __restrict__ wRb,
    float* __restrict__ acc)
{
    __shared__ float hs[CCH][ROWS+2][26];
    __shared__ float scl[CCH][ROWS+2];
    int bx = blockIdx.x;
    int og = blockIdx.y;
    int cs = blockIdx.z;
    int n  = bx / (HP/ROWS);
    int r0 = (bx % (HP/ROWS))*ROWS;
    int tid = threadIdx.x;
    int c0 = cs*CCH;

    if (tid < CCH*(ROWS+2)){
        int c = tid/(ROWS+2), j = tid%(ROWS+2);
        int row = r0 + j - 1;
        float s = 0.f;
        if (row >= 0 && row < HP){
            const float* xp = x + (long)n*nStr + (long)(c0+c)*cStr + row*WP;
            #pragma unroll
            for (int w = 0; w < WP; w++){ float v = xp[w]; s += v*v; }
            s = rsqrtf(s*(1.0f/WP) + 1e-5f) * nw[c0+c];
        }
        scl[c][j] = s;
    }
    __syncthreads();

    for (int idx = tid; idx < CCH*(ROWS+2)*26; idx += 256){
        int c = idx/((ROWS+2)*26); int rem = idx%((ROWS+2)*26); int j = rem/26; int wc = rem%26;
        int row = r0 + j - 1;
        float v = 0.f;
        if (row >= 0 && row < HP && wc >= 1 && wc <= WP)
            v = x[(long)n*nStr + (long)(c0+c)*cStr + row*WP + (wc-1)] * scl[c][j];
        hs[c][j][wc] = v;
    }
    __syncthreads();

    int ol = tid & 63;
    int o  = og*64 + ol;
    int x0 = (tid >> 6) * 6;
    float a0[6] = {0,0,0,0,0,0};
    float a1[6] = {0,0,0,0,0,0};
    const uint4* wq4 = (const uint4*)wQb;

    for (int c = 0; c < CCH; c++){
        int cg = c0 + c;
        uint4 wv = wq4[cg*CO + o];
        float w0 = bflo(wv.x), w1 = bfhi(wv.x);
        float w2 = bflo(wv.y), w3 = bfhi(wv.y);
        float w4 = bflo(wv.z), w5 = bfhi(wv.z);
        float w6 = bflo(wv.w), w7 = bfhi(wv.w);
        float w8 = bflo((unsigned)wRb[cg*CO + o]);
        float r0v[8], r1v[8], r2v[8], r3v[8];
        #pragma unroll
        for (int i = 0; i < 8; i++){
            r0v[i] = hs[c][0][x0+i]; r1v[i] = hs[c][1][x0+i];
            r2v[i] = hs[c][2][x0+i]; r3v[i] = hs[c][3][x0+i];
        }
        #pragma unroll
        for (int p = 0; p < 6; p++){
            a0[p] += w0*r0v[p] + w1*r0v[p+1] + w2*r0v[p+2]
                   + w3*r1v[p] + w4*r1v[p+1] + w5*r1v[p+2]
                   + w6*r2v[p] + w7*r2v[p+1] + w8*r2v[p+2];
            a1[p] += w0*r1v[p] + w1*r1v[p+1] + w2*r1v[p+2]
                   + w3*r2v[p] + w4*r2v[p+1] + w5*r2v[p+2]
                   + w6*r3v[p] + w7*r3v[p+1] + w8*r3v[p+2];
        }
    }

    float* ap0 = acc + ((long)(cs*NB + n)*PX + r0*WP + x0)*CO + o;
    float* ap1 = ap0 + (long)WP*CO;
    #pragma unroll
    for (int p = 0; p < 6; p++){ ap0[p*CO] = a0[p]; ap1[p*CO] = a1[p]; }
}

// ---- ssmproj: sum partials -> conv1d tap + SiLU gates -> x_proj/dt/BC -> gate ->
//               out_proj + residual. block 256 = 4 waves = 4 pixels; grid NB*PX/4.
__global__ __launch_bounds__(256) void ssmproj_k(
    const float* __restrict__ acc,
    const float* __restrict__ c1w, const float* __restrict__ c1b,
    const float* __restrict__ xpw, const float* __restrict__ dtw,
    const float* __restrict__ dtb, const float* __restrict__ Dp,
    const float* __restrict__ wpT,
    const float* __restrict__ xres, long nStrR, long cStrR,
    float* __restrict__ dst)
{
    __shared__ float gl[4][CI];
    int wave = threadIdx.x >> 6, lane = threadIdx.x & 63;
    int p0 = blockIdx.x*4;
    int p  = p0 + wave;
    int n  = p / PX, px = p % PX;

    float xi[3], sz[3];
    #pragma unroll
    for (int t = 0; t < 3; t++){
        int c = lane + 64*t;
        float xr = 0.f, zr = 0.f;
        #pragma unroll
        for (int q = 0; q < CSPLIT; q++){
            const float* ap = acc + ((long)(q*NB + n)*PX + px)*CO;
            xr += ap[c]; zr += ap[CI + c];
        }
        xi[t] = siluf(xr*c1w[c*4 + 3] + c1b[c]);
        sz[t] = siluf(zr);
    }

    float dbc[NDBC];
    #pragma unroll
    for (int j = 0; j < NDBC; j++){
        float s = 0.f;
        #pragma unroll
        for (int t = 0; t < 3; t++) s += xi[t]*xpw[j*CI + lane + 64*t];
        dbc[j] = s;
    }
    #pragma unroll
    for (int step = 1; step < 64; step <<= 1){
        #pragma unroll
        for (int j = 0; j < NDBC; j++) dbc[j] += __shfl_xor(dbc[j], step, 64);
    }
    float BC = 0.f;
    #pragma unroll
    for (int s = 0; s < 16; s++) BC += dbc[6+s]*dbc[22+s];

    #pragma unroll
    for (int t = 0; t < 3; t++){
        int c = lane + 64*t;
        float dl = dtb[c];
        #pragma unroll
        for (int r = 0; r < DTR; r++) dl += dbc[r]*dtw[c*DTR + r];
        dl = softplusf(dl);
        gl[wave][c] = xi[t]*(dl*BC + Dp[c])*sz[t];
    }
    __syncthreads();

    for (int idx = threadIdx.x; idx < 4*CM; idx += 256){
        int pl = idx / CM, m = idx % CM;
        int pp = p0 + pl;
        int nn = pp / PX, ppx = pp % PX;
        const float* g = gl[pl];
        float s0 = 0.f, s1 = 0.f, s2 = 0.f, s3 = 0.f;
        for (int c = 0; c < CI; c += 4){
            s0 += g[c+0]*wpT[(c+0)*CM + m];
            s1 += g[c+1]*wpT[(c+1)*CM + m];
            s2 += g[c+2]*wpT[(c+2)*CM + m];
            s3 += g[c+3]*wpT[(c+3)*CM + m];
        }
        float s = (s0+s1) + (s2+s3);
        s += xres[(long)nn*nStrR + (long)m*cStrR + ppx];
        dst[(nn*CM + m)*PX + ppx] = s;
    }
}

extern "C" void kernel_launch(void* const* d_in, const int* in_sizes, int n_in,
                              void* d_out, int out_size, void* d_ws, size_t ws_size,
                              hipStream_t stream) {
    const float* x_in = (const float*)d_in[0];   // (2,96,8,24,24)
    const float* ipw  = (const float*)d_in[1];   // (2,384,96,1,3,3)
    const float* c1w  = (const float*)d_in[2];   // (2,192,1,4,1,1)
    const float* c1b  = (const float*)d_in[3];   // (2,192)
    const float* xpw  = (const float*)d_in[4];   // (2,38,192)
    const float* dtw  = (const float*)d_in[5];   // (2,192,6)
    const float* dtb  = (const float*)d_in[6];   // (2,192)
    // d_in[7] = A_log: unused at depth 0 (multiplies h[-1]=0)
    const float* Dp   = (const float*)d_in[8];   // (2,192)
    const float* opw  = (const float*)d_in[9];   // (2,96,192)
    const float* nw   = (const float*)d_in[10];  // (2,1,96,1,1,1)

    char* ws = (char*)d_ws;
    unsigned short* wQb = (unsigned short*)ws;              // 2*294912 ush = 1179648 B
    unsigned short* wRb = wQb + 2*WQB_L;                    // 2*36864 ush  = 147456 B
    float* wpT = (float*)(wRb + 2*WRB_L);                   // 2*18432 f    = 147456 B
    float* acc = wpT + 2*WPT_L;                             // 4*2*576*384 f = 7077888 B
    float* x1  = acc + (long)CSPLIT*NB*PX*CO;               // 110592 f

    prep_k<<<(NW_IN + 2*CI*CM + 255)/256, 256, 0, stream>>>(ipw, opw, wQb, wRb, wpT);

    // ---- layer 0 (input: depth-0 slice of x, strides of (2,96,8,24,24))
    conv_k<<<dim3(NB*(HP/ROWS), 6, CSPLIT), 256, 0, stream>>>(
        x_in, 96L*8*PX, 8L*PX, nw, wQb, wRb, acc);
    ssmproj_k<<<NB*PX/4, 256, 0, stream>>>(
        acc, c1w, c1b, xpw, dtw, dtb, Dp, wpT,
        x_in, 96L*8*PX, 8L*PX, x1);

    // ---- layer 1 (input x1 packed (2,96,24,24); writes final output)
    conv_k<<<dim3(NB*(HP/ROWS), 6, CSPLIT), 256, 0, stream>>>(
        x1, 96L*PX, (long)PX, nw + CM, wQb + WQB_L, wRb + WRB_L, acc);
    ssmproj_k<<<NB*PX/4, 256, 0, stream>>>(
        acc, c1w + CI*4, c1b + CI, xpw + NDBC*CI, dtw + CI*DTR, dtb + CI, Dp + CI, wpT + WPT_L,
        x1, 96L*PX, (long)PX, (float*)d_out);
}

// Round 4
// 161.520 us; speedup vs baseline: 1.0727x; 1.0727x over previous
//
#include <hip/hip_runtime.h>
#include <math.h>

// Depth collapses to d=0 (x[:, :, 0:1] slicing): conv1d -> w[3]*xi+b,
// scan at d=0 -> hs[0]=BX[0] (A_log unused), y = xi*(delta*sum(B*C)+D).
#define NB   2
#define CM   96      // D_MODEL
#define CI   192     // D_INNER
#define CO   384     // 2*D_INNER
#define HP   24
#define WP   24
#define PX   576
#define DTR  6
#define NDBC 38
#define CSPLIT 8
#define CCH  12      // input channels per conv chunk (96/CSPLIT)

__device__ __forceinline__ float siluf(float x){ return x / (1.f + expf(-x)); }
__device__ __forceinline__ float softplusf(float x){ return x > 20.f ? x : log1pf(expf(x)); }
__device__ __forceinline__ unsigned short f2bf(float f){
    unsigned u = __float_as_uint(f);
    return (unsigned short)((u + 0x7fffu + ((u >> 16) & 1u)) >> 16);
}
__device__ __forceinline__ float bflo(unsigned u){ return __uint_as_float(u << 16); }
__device__ __forceinline__ float bfhi(unsigned u){ return __uint_as_float(u & 0xffff0000u); }

// ---- prep: pack in_proj weights to bf16: wQb[l][c][o][k0..7] (ushort8 = uint4)
//            + wRb[l][c][o] (tap 8), and transpose out_proj -> wpT[l][c][m] fp32
#define NW_IN (2*CO*CM*9)      // 663552
#define WQB_L (CM*CO*8)        // ushorts per layer
#define WRB_L (CM*CO)
#define WPT_L (CI*CM)
__global__ void prep_k(const float* __restrict__ ipw, const float* __restrict__ opw,
                       unsigned short* __restrict__ wQb, unsigned short* __restrict__ wRb,
                       float* __restrict__ wpT){
    int idx = blockIdx.x*256 + threadIdx.x;
    if (idx < NW_IN){
        int l = idx / (CO*CM*9);
        int r = idx % (CO*CM*9);
        int o = r / (CM*9);
        int r2 = r % (CM*9);
        int c = r2 / 9;
        int k = r2 % 9;
        unsigned short v = f2bf(ipw[idx]);
        if (k < 8) wQb[(long)l*WQB_L + ((c*CO + o)<<3) + k] = v;
        else       wRb[(long)l*WRB_L + c*CO + o] = v;
    } else {
        int j = idx - NW_IN;
        if (j < 2*CI*CM){
            int l = j / (CI*CM);
            int r = j % (CI*CM);
            int c = r / CM;
            int m = r % CM;
            wpT[l*WPT_L + c*CM + m] = opw[(l*CM + m)*CI + c];
        }
    }
}

// ---- conv: fused rmsnorm + 3x3 conv (pad 1), bf16 weights, fp32 accum.
// grid (NB*HP, 6 o-groups, CSPLIT c-chunks), block 256 (4 waves x 6-px strips).
// acc layout: [cs][n][px][o]
__global__ __launch_bounds__(256) void conv_k(
    const float* __restrict__ x, long nStr, long cStr,
    const float* __restrict__ nw,
    const unsigned short* __restrict__ wQb, const unsigned short* __restrict__ wRb,
    float* __restrict__ acc)
{
    __shared__ float hs[CCH][3][28];   // 28-wide rows: every (c,j) row base 16B-aligned
    __shared__ float scl[CCH][3];
    int bx = blockIdx.x;
    int og = blockIdx.y;
    int cs = blockIdx.z;
    int n  = bx / HP, hh = bx % HP;
    int tid = threadIdx.x;
    int c0 = cs*CCH;

    if (tid < CCH*3){
        int c = tid/3, j = tid%3;
        int row = hh + j - 1;
        float s = 0.f;
        if (row >= 0 && row < HP){
            const float* xp = x + (long)n*nStr + (long)(c0+c)*cStr + row*WP;
            #pragma unroll
            for (int w = 0; w < WP; w++){ float v = xp[w]; s += v*v; }
            s = rsqrtf(s*(1.0f/WP) + 1e-5f) * nw[c0+c];
        }
        scl[c][j] = s;
    }
    __syncthreads();

    for (int idx = tid; idx < CCH*3*28; idx += 256){
        int c = idx/84; int rem = idx%84; int j = rem/28; int wc = rem%28;
        int row = hh + j - 1;
        float v = 0.f;
        if (row >= 0 && row < HP && wc >= 1 && wc <= WP)
            v = x[(long)n*nStr + (long)(c0+c)*cStr + row*WP + (wc-1)] * scl[c][j];
        hs[c][j][wc] = v;
    }
    __syncthreads();

    int ol = tid & 63;
    int o  = og*64 + ol;
    int x0 = (tid >> 6) * 6;           // even -> 8B-aligned float2 loads
    float a0[6] = {0,0,0,0,0,0};
    const uint4* wq4 = (const uint4*)wQb;

    for (int c = 0; c < CCH; c++){
        int cg = c0 + c;
        uint4 wv = wq4[cg*CO + o];
        float w0 = bflo(wv.x), w1 = bfhi(wv.x);
        float w2 = bflo(wv.y), w3 = bfhi(wv.y);
        float w4 = bflo(wv.z), w5 = bfhi(wv.z);
        float w6 = bflo(wv.w), w7 = bfhi(wv.w);
        float w8 = bflo((unsigned)wRb[cg*CO + o]);
        float r0v[8], r1v[8], r2v[8];
        #pragma unroll
        for (int i = 0; i < 4; i++){
            float2 p0 = *(const float2*)(&hs[c][0][x0] + 2*i);
            float2 p1 = *(const float2*)(&hs[c][1][x0] + 2*i);
            float2 p2 = *(const float2*)(&hs[c][2][x0] + 2*i);
            r0v[2*i] = p0.x; r0v[2*i+1] = p0.y;
            r1v[2*i] = p1.x; r1v[2*i+1] = p1.y;
            r2v[2*i] = p2.x; r2v[2*i+1] = p2.y;
        }
        #pragma unroll
        for (int p = 0; p < 6; p++){
            a0[p] += w0*r0v[p] + w1*r0v[p+1] + w2*r0v[p+2]
                   + w3*r1v[p] + w4*r1v[p+1] + w5*r1v[p+2]
                   + w6*r2v[p] + w7*r2v[p+1] + w8*r2v[p+2];
        }
    }

    float* ap = acc + ((long)(cs*NB + n)*PX + hh*WP + x0)*CO + o;
    #pragma unroll
    for (int p = 0; p < 6; p++) ap[p*CO] = a0[p];
}

// ---- ssmproj: sum partials -> conv1d tap + SiLU gates -> x_proj/dt/BC -> gate ->
//               out_proj + residual. block 256 = 4 waves = 4 pixels; grid NB*PX/4.
__global__ __launch_bounds__(256) void ssmproj_k(
    const float* __restrict__ acc,
    const float* __restrict__ c1w, const float* __restrict__ c1b,
    const float* __restrict__ xpw, const float* __restrict__ dtw,
    const float* __restrict__ dtb, const float* __restrict__ Dp,
    const float* __restrict__ wpT,
    const float* __restrict__ xres, long nStrR, long cStrR,
    float* __restrict__ dst)
{
    __shared__ float gl[4][CI];
    int wave = threadIdx.x >> 6, lane = threadIdx.x & 63;
    int p0 = blockIdx.x*4;
    int p  = p0 + wave;
    int n  = p / PX, px = p % PX;

    float xi[3], sz[3];
    #pragma unroll
    for (int t = 0; t < 3; t++){
        int c = lane + 64*t;
        float xr = 0.f, zr = 0.f;
        #pragma unroll
        for (int q = 0; q < CSPLIT; q++){
            const float* ap = acc + ((long)(q*NB + n)*PX + px)*CO;
            xr += ap[c]; zr += ap[CI + c];
        }
        xi[t] = siluf(xr*c1w[c*4 + 3] + c1b[c]);
        sz[t] = siluf(zr);
    }

    float dbc[NDBC];
    #pragma unroll
    for (int j = 0; j < NDBC; j++){
        float s = 0.f;
        #pragma unroll
        for (int t = 0; t < 3; t++) s += xi[t]*xpw[j*CI + lane + 64*t];
        dbc[j] = s;
    }
    #pragma unroll
    for (int step = 1; step < 64; step <<= 1){
        #pragma unroll
        for (int j = 0; j < NDBC; j++) dbc[j] += __shfl_xor(dbc[j], step, 64);
    }
    float BC = 0.f;
    #pragma unroll
    for (int s = 0; s < 16; s++) BC += dbc[6+s]*dbc[22+s];

    #pragma unroll
    for (int t = 0; t < 3; t++){
        int c = lane + 64*t;
        float dl = dtb[c];
        #pragma unroll
        for (int r = 0; r < DTR; r++) dl += dbc[r]*dtw[c*DTR + r];
        dl = softplusf(dl);
        gl[wave][c] = xi[t]*(dl*BC + Dp[c])*sz[t];
    }
    __syncthreads();

    for (int idx = threadIdx.x; idx < 4*CM; idx += 256){
        int pl = idx / CM, m = idx % CM;
        int pp = p0 + pl;
        int nn = pp / PX, ppx = pp % PX;
        const float* g = gl[pl];
        float s0 = 0.f, s1 = 0.f, s2 = 0.f, s3 = 0.f;
        for (int c = 0; c < CI; c += 4){
            s0 += g[c+0]*wpT[(c+0)*CM + m];
            s1 += g[c+1]*wpT[(c+1)*CM + m];
            s2 += g[c+2]*wpT[(c+2)*CM + m];
            s3 += g[c+3]*wpT[(c+3)*CM + m];
        }
        float s = (s0+s1) + (s2+s3);
        s += xres[(long)nn*nStrR + (long)m*cStrR + ppx];
        dst[(nn*CM + m)*PX + ppx] = s;
    }
}

extern "C" void kernel_launch(void* const* d_in, const int* in_sizes, int n_in,
                              void* d_out, int out_size, void* d_ws, size_t ws_size,
                              hipStream_t stream) {
    const float* x_in = (const float*)d_in[0];   // (2,96,8,24,24)
    const float* ipw  = (const float*)d_in[1];   // (2,384,96,1,3,3)
    const float* c1w  = (const float*)d_in[2];   // (2,192,1,4,1,1)
    const float* c1b  = (const float*)d_in[3];   // (2,192)
    const float* xpw  = (const float*)d_in[4];   // (2,38,192)
    const float* dtw  = (const float*)d_in[5];   // (2,192,6)
    const float* dtb  = (const float*)d_in[6];   // (2,192)
    // d_in[7] = A_log: unused at depth 0 (multiplies h[-1]=0)
    const float* Dp   = (const float*)d_in[8];   // (2,192)
    const float* opw  = (const float*)d_in[9];   // (2,96,192)
    const float* nw   = (const float*)d_in[10];  // (2,1,96,1,1,1)

    char* ws = (char*)d_ws;
    unsigned short* wQb = (unsigned short*)ws;              // 2*294912 ush = 1179648 B
    unsigned short* wRb = wQb + 2*WQB_L;                    // 2*36864 ush  = 147456 B
    float* wpT = (float*)(wRb + 2*WRB_L);                   // 2*18432 f    = 147456 B
    float* acc = wpT + 2*WPT_L;                             // 8*2*576*384 f = 14155776 B
    float* x1  = acc + (long)CSPLIT*NB*PX*CO;               // 110592 f

    prep_k<<<(NW_IN + 2*CI*CM + 255)/256, 256, 0, stream>>>(ipw, opw, wQb, wRb, wpT);

    // ---- layer 0 (input: depth-0 slice of x, strides of (2,96,8,24,24))
    conv_k<<<dim3(NB*HP, 6, CSPLIT), 256, 0, stream>>>(
        x_in, 96L*8*PX, 8L*PX, nw, wQb, wRb, acc);
    ssmproj_k<<<NB*PX/4, 256, 0, stream>>>(
        acc, c1w, c1b, xpw, dtw, dtb, Dp, wpT,
        x_in, 96L*8*PX, 8L*PX, x1);

    // ---- layer 1 (input x1 packed (2,96,24,24); writes final output)
    conv_k<<<dim3(NB*HP, 6, CSPLIT), 256, 0, stream>>>(
        x1, 96L*PX, (long)PX, nw + CM, wQb + WQB_L, wRb + WRB_L, acc);
    ssmproj_k<<<NB*PX/4, 256, 0, stream>>>(
        acc, c1w + CI*4, c1b + CI, xpw + NDBC*CI, dtw + CI*DTR, dtb + CI, Dp + CI, wpT + WPT_L,
        x1, 96L*PX, (long)PX, (float*)d_out);
}